// Round 1
// 523.980 us; speedup vs baseline: 1.0657x; 1.0657x over previous
//
#include <hip/hip_runtime.h>
#include <cstdint>
#include <cstddef>

// ---------------------------------------------------------------------------
// ChunkedCrossAttention: h(4,2048,1024), e(4,32,2,128,1024)
// LN(h[:,63:]) -> Q; e -> fused KV GEMM (N=2048, V pre-transposed per head);
// per-(b,chunk,head) attn over 256 keys; O-proj + shifted residual.
// KV GEMM upgraded to the 256x256 8-phase template (T2 swizzle + T3/T4
// counted vmcnt + T5 setprio). Q/O remain on the 128x128 kernel.
// Workspace exactly 184 MiB.
// ---------------------------------------------------------------------------

typedef float f32x4 __attribute__((ext_vector_type(4)));
typedef __bf16 bf16x8 __attribute__((ext_vector_type(8)));

static __device__ __forceinline__ ushort f2bf(float f) {
  union { float f; uint32_t u; } x; x.f = f;
  uint32_t r = x.u + 0x7fffu + ((x.u >> 16) & 1u);   // RTNE
  return (ushort)(r >> 16);
}

static __device__ __forceinline__ bf16x8 ld_frag(const ushort* p) {
  union { uint4 u; bf16x8 v; } x;
  x.u = *(const uint4*)p;
  return x.v;
}

// async global->LDS, 16 B per lane (proven working).
static __device__ __forceinline__ void gl2lds16(const ushort* g, ushort* l) {
  __builtin_amdgcn_global_load_lds(
      (const __attribute__((address_space(1))) void*)g,
      (__attribute__((address_space(3))) void*)l,
      16, 0, 0);
}

// ---------------------------------------------------------------------------
// Weight transpose + cast, all 4 weights in one dispatch (z selects).
// ---------------------------------------------------------------------------
__global__ __launch_bounds__(256) void transpose_cast4(const float* __restrict__ Wq,
                                                       const float* __restrict__ Wk,
                                                       const float* __restrict__ Wv,
                                                       const float* __restrict__ Wo,
                                                       ushort* __restrict__ WqT,
                                                       ushort* __restrict__ WkvT,
                                                       ushort* __restrict__ WoT) {
  const float* W; ushort* WT;
  switch (blockIdx.z) {
    case 0:  W = Wq; WT = WqT; break;
    case 1:  W = Wk; WT = WkvT; break;
    case 2:  W = Wv; WT = WkvT + (size_t)1024 * 1024; break;
    default: W = Wo; WT = WoT; break;
  }
  __shared__ float tile[64][65];
  const int t = threadIdx.x;
  const int n0 = blockIdx.x * 64, k0 = blockIdx.y * 64;
#pragma unroll
  for (int i = 0; i < 4; ++i) {
    int lid = i * 256 + t;
    int r = lid >> 4, c4 = (lid & 15) * 4;
    float4 v = *(const float4*)&W[(size_t)(k0 + r) * 1024 + n0 + c4];
    tile[r][c4 + 0] = v.x; tile[r][c4 + 1] = v.y;
    tile[r][c4 + 2] = v.z; tile[r][c4 + 3] = v.w;
  }
  __syncthreads();
#pragma unroll
  for (int i = 0; i < 4; ++i) {
    int lid = i * 256 + t;
    int n = lid >> 4, k4 = (lid & 15) * 4;
    ushort4 o;
    o.x = f2bf(tile[k4 + 0][n]); o.y = f2bf(tile[k4 + 1][n]);
    o.z = f2bf(tile[k4 + 2][n]); o.w = f2bf(tile[k4 + 3][n]);
    *(ushort4*)&WT[(size_t)(n0 + n) * 1024 + k0 + k4] = o;
  }
}

// ---------------------------------------------------------------------------
// cast f32 -> bf16, 8 elems/thread
// ---------------------------------------------------------------------------
__global__ __launch_bounds__(256) void cast_bf16(const float* __restrict__ x,
                                                 ushort* __restrict__ y) {
  const size_t i = ((size_t)blockIdx.x * 256 + threadIdx.x) * 8;
  float4 a = *(const float4*)&x[i];
  float4 b = *(const float4*)&x[i + 4];
  ushort o[8];
  o[0] = f2bf(a.x); o[1] = f2bf(a.y); o[2] = f2bf(a.z); o[3] = f2bf(a.w);
  o[4] = f2bf(b.x); o[5] = f2bf(b.y); o[6] = f2bf(b.z); o[7] = f2bf(b.w);
  *(uint4*)&y[i] = *(const uint4*)o;
}

// ---------------------------------------------------------------------------
// LayerNorm: hh[b, s, :] = LN(h[b, 63+s, :]) for s<1985 else 0   (bf16 out)
// ---------------------------------------------------------------------------
__global__ __launch_bounds__(256) void ln_kernel(const float* __restrict__ h,
                                                 const float* __restrict__ gamma,
                                                 const float* __restrict__ beta,
                                                 ushort* __restrict__ hh) {
  const int bx = blockIdx.x;
  const int b = bx >> 11, s = bx & 2047;
  const int t = threadIdx.x;
  ushort* orow = hh + (size_t)(b * 2048 + s) * 1024;
  if (s >= 1985) {
    ushort4 z; z.x = 0; z.y = 0; z.z = 0; z.w = 0;
    *(ushort4*)&orow[t * 4] = z;
    return;
  }
  const float* xrow = h + (size_t)(b * 2048 + 63 + s) * 1024;
  float4 x = *(const float4*)&xrow[t * 4];
  float s1 = x.x + x.y + x.z + x.w;
  float s2 = x.x * x.x + x.y * x.y + x.z * x.z + x.w * x.w;
#pragma unroll
  for (int off = 32; off > 0; off >>= 1) {
    s1 += __shfl_xor(s1, off);
    s2 += __shfl_xor(s2, off);
  }
  __shared__ float a1[4], a2[4];
  if ((t & 63) == 0) { a1[t >> 6] = s1; a2[t >> 6] = s2; }
  __syncthreads();
  s1 = a1[0] + a1[1] + a1[2] + a1[3];
  s2 = a2[0] + a2[1] + a2[2] + a2[3];
  const float mu = s1 * (1.0f / 1024.0f);
  const float var = s2 * (1.0f / 1024.0f) - mu * mu;
  const float rstd = rsqrtf(var + 1e-5f);
  float4 g = *(const float4*)&gamma[t * 4];
  float4 be = *(const float4*)&beta[t * 4];
  ushort4 o;
  o.x = f2bf((x.x - mu) * rstd * g.x + be.x);
  o.y = f2bf((x.y - mu) * rstd * g.y + be.y);
  o.z = f2bf((x.z - mu) * rstd * g.z + be.z);
  o.w = f2bf((x.w - mu) * rstd * g.w + be.w);
  *(ushort4*)&orow[t * 4] = o;
}

// ---------------------------------------------------------------------------
// 128x128 GEMM (kept for Q and O projections).
//  MODE 0 (NT=8):  C -> bf16 row-major, post-scale (Q, scale=1/8)
//  MODE 1 (NT=8):  f32 out with shifted residual add (O-proj).
// ---------------------------------------------------------------------------
template <int MODE, int NT>
__global__ __launch_bounds__(256) void gemm_bf16(const ushort* __restrict__ A,
                                                 const ushort* __restrict__ Bt,
                                                 const float* __restrict__ bias,
                                                 const float* __restrict__ bias2,
                                                 ushort* __restrict__ Cbf,
                                                 ushort* __restrict__ Vtg,
                                                 float* __restrict__ Cf,
                                                 const float* __restrict__ resid,
                                                 int mtiles, float scale,
                                                 int mrow_off) {
  __shared__ __align__(16) ushort Alds[2][128 * 32];
  __shared__ __align__(16) ushort Blds[2][128 * 32];
  const int t = threadIdx.x;
  const int lane = t & 63, wave = t >> 6;
  const int quad = lane >> 4, l16 = lane & 15;

  const int L = blockIdx.x;
  const int xcd = L & 7, slot = L >> 3;
  const int nt = slot & (NT - 1);
  const int mt = xcd * (mtiles >> 3) + (slot / NT);
  const int m0 = mt * 128, n0 = nt * 128;

  const int srow = lane >> 2;
  const int scol = (lane & 3) * 8;
  const int c0 = wave * 2;
  const ushort* gA0 = A  + (size_t)(m0 + c0 * 16 + srow) * 1024 + scol;
  const ushort* gA1 = gA0 + 16 * 1024;
  const ushort* gB0 = Bt + (size_t)(n0 + c0 * 16 + srow) * 1024 + scol;
  const ushort* gB1 = gB0 + 16 * 1024;
  ushort* dA0 = &Alds[0][c0 * 512 + lane * 8];
  ushort* dA1 = dA0 + 512;
  ushort* dB0 = &Blds[0][c0 * 512 + lane * 8];
  ushort* dB1 = dB0 + 512;
  const ptrdiff_t SUB = 128 * 32;

  const int wrow = (wave >> 1) * 64, wcol = (wave & 1) * 64;
  const ushort* pA = &Alds[0][(wrow + l16) * 32 + quad * 8];
  const ushort* pB = &Blds[0][(wcol + l16) * 32 + quad * 8];

  f32x4 zero = {0.f, 0.f, 0.f, 0.f};
  f32x4 acc[4][4];
#pragma unroll
  for (int i = 0; i < 4; ++i)
#pragma unroll
    for (int j = 0; j < 4; ++j) acc[i][j] = zero;

  for (int kb = 0; kb < 16; ++kb) {
    const int ko = kb * 64;
    gl2lds16(gA0 + ko, dA0);         gl2lds16(gA1 + ko, dA1);
    gl2lds16(gA0 + ko + 32, dA0 + SUB); gl2lds16(gA1 + ko + 32, dA1 + SUB);
    gl2lds16(gB0 + ko, dB0);         gl2lds16(gB1 + ko, dB1);
    gl2lds16(gB0 + ko + 32, dB0 + SUB); gl2lds16(gB1 + ko + 32, dB1 + SUB);
    __syncthreads();
#pragma unroll
    for (int sub = 0; sub < 2; ++sub) {
      bf16x8 af[4], bfv[4];
#pragma unroll
      for (int i = 0; i < 4; ++i) af[i]  = ld_frag(pA + sub * SUB + i * 512);
#pragma unroll
      for (int j = 0; j < 4; ++j) bfv[j] = ld_frag(pB + sub * SUB + j * 512);
#pragma unroll
      for (int i = 0; i < 4; ++i)
#pragma unroll
        for (int j = 0; j < 4; ++j)
          acc[i][j] = __builtin_amdgcn_mfma_f32_16x16x32_bf16(af[i], bfv[j], acc[i][j], 0, 0, 0);
    }
    __syncthreads();
  }

#pragma unroll
  for (int mi = 0; mi < 4; ++mi)
#pragma unroll
    for (int mj = 0; mj < 4; ++mj) {
      const int cc = n0 + wcol + mj * 16 + l16;
      const int r0 = m0 + wrow + mi * 16 + quad * 4;
      if constexpr (MODE == 0) {
        const float bvb = bias[cc];
#pragma unroll
        for (int rr = 0; rr < 4; ++rr)
          Cbf[(size_t)(r0 + rr) * 1024 + cc] = f2bf((acc[mi][mj][rr] + bvb) * scale);
      } else {          // MODE 1: f32 out + shifted residual
        const float bvb = bias[cc];
#pragma unroll
        for (int rr = 0; rr < 4; ++rr) {
          const int r = r0 + rr;
          const int b = r >> 11, s = r & 2047;
          if (s < 1985) {
            const size_t o = (size_t)(b * 2048 + s + 63) * 1024 + cc;
            Cf[o] = acc[mi][mj][rr] + bvb + resid[o];
          }
        }
      }
    }
}

// ---------------------------------------------------------------------------
// Fused KV GEMM, 256x256 8-phase template (plain-HIP port of the verified
// m201 schedule):
//   M=16384 (per half), N=2048 (cols 0-1023 -> K row-major, 1024-2047 -> V
//   transposed per head), K=1024 (16 K-tiles of BK=64).
//   8 waves (2Mx4N), 512 threads, per-wave output 128x64, acc[8][4].
//   LDS 128 KiB: 2 dbuf x 2 halves x [128][64] x {A,B}.
//   Per K-tile: 4 phases {ds_reads || stage 1 half-tile -> barrier ->
//   lgkmcnt(0) -> setprio(1) -> 16 MFMA -> setprio(0) -> barrier}; one
//   counted s_waitcnt vmcnt(6) per K-tile boundary (3 half-tiles in flight),
//   vmcnt(0) only before the final tile.
//   Quadrant schedule (reads 12/4/8/0) makes current-buffer halves dead
//   early: B-halves after P1, A-halves after P2 -> staging tile t+2 into the
//   CURRENT buffer at P2/P3 is race-free (writes land after last reader's
//   lgkmcnt(0)+barrier).
//   Bank-conflict swizzle (G4 form): 16B-slot ^= (row&7) on 128-B rows.
//   st_16x32's single-bit XOR is a no-op for this frag pattern (quads
//   already cover all slot-pairs); the 3-bit XOR gives uniform 8 lanes/slot
//   per ds_read_b128 (the b128 minimum). Applied as linear LDS dest +
//   inverse-swizzled GLOBAL source (global_load_lds constraint) + swizzled
//   read address; swizzle bits collapse to per-thread constants.
// ---------------------------------------------------------------------------
__global__ __launch_bounds__(512, 2) void gemm_kv256(const ushort* __restrict__ A,
                                                     const ushort* __restrict__ Bt,
                                                     const float* __restrict__ bk_,
                                                     const float* __restrict__ bv_,
                                                     ushort* __restrict__ Kout,
                                                     ushort* __restrict__ Vtg,
                                                     int mrow_off) {
  __shared__ __align__(16) ushort Alds[4 * 8192];   // 64 KiB
  __shared__ __align__(16) ushort Blds[4 * 8192];   // 64 KiB

  const int t = threadIdx.x;
  const int lane = t & 63, wave = t >> 6;          // 8 waves
  const int wm = wave >> 2, wn = wave & 3;         // 2 x 4
  const int l16 = lane & 15, quad = lane >> 4;

  // XCD swizzle: 512 blocks, each XCD owns 8 contiguous m-tiles x all 8 n.
  const int L = blockIdx.x;
  const int xcd = L & 7, slot = L >> 3;
  const int nt = slot & 7, mt = xcd * 8 + (slot >> 3);
  const int m0 = mt * 256, n0 = nt * 256;

  // ---- staging geometry (inverse-swizzled global source, linear LDS) ----
  // Half-tile = 128 rows x 64 cols bf16 = 16 KiB; wave w covers chunks
  // {2w, 2w+1} of 8 rows each; lane covers (row = lane>>3, 16B col slot
  // (lane&7) ^ (lane>>3)).
  const int w2 = wave * 2;
  const int srow = lane >> 3;                       // 0..7
  const int lanex = (lane & 7) ^ srow;              // inverse swizzle
  const ushort* gA2 = A  + (size_t)(m0 + w2 * 8 + srow) * 1024 + lanex * 8;
  const ushort* gB2 = Bt + (size_t)(n0 + w2 * 8 + srow) * 1024 + lanex * 8;
  ushort* dA2 = Alds + w2 * 512 + lane * 8;
  ushort* dB2 = Blds + w2 * 512 + lane * 8;

  auto stage_a = [&](int ti, int hh) {
    const ushort* g = gA2 + (size_t)hh * 131072 + (size_t)ti * 64;
    ushort* d = dA2 + ((ti & 1) * 2 + hh) * 8192;
    gl2lds16(g, d);
    gl2lds16(g + 8192, d + 512);
  };
  auto stage_b = [&](int ti, int hh) {
    const ushort* g = gB2 + (size_t)hh * 131072 + (size_t)ti * 64;
    ushort* d = dB2 + ((ti & 1) * 2 + hh) * 8192;
    gl2lds16(g, d);
    gl2lds16(g + 8192, d + 512);
  };

  // ---- read geometry (swizzled): layout col = (ks^b2)*32 + (quad^(l16&3))*8
  const int b2 = (l16 >> 2) & 1;
  const int qx = (quad ^ (l16 & 3)) << 3;
  const int kof0 = b2 << 5;
  const int kof1 = 32 - kof0;

  f32x4 zero = {0.f, 0.f, 0.f, 0.f};
  f32x4 acc[8][4];
#pragma unroll
  for (int i = 0; i < 8; ++i)
#pragma unroll
    for (int j = 0; j < 4; ++j) acc[i][j] = zero;

  // ---- prologue: tile 0 fully + first 3 half-tiles of tile 1 ----
  stage_b(0, 0); stage_a(0, 0); stage_b(0, 1); stage_a(0, 1);
  stage_b(1, 0); stage_a(1, 0); stage_b(1, 1);
  asm volatile("s_waitcnt vmcnt(6)" ::: "memory");   // tile0 done, 3 ht in flight
  __builtin_amdgcn_s_barrier();

  bf16x8 a[4][2], b01[2][2], b23[2][2];

#pragma unroll 2
  for (int tt = 0; tt < 16; ++tt) {
    const int cur = tt & 1;
    const ushort* pa = Alds + (cur * 2 + wm) * 8192 + l16 * 64 + qx;
    const ushort* pb = Blds + (cur * 2 + (wn >> 1)) * 8192 +
                       ((wn & 1) * 64 + l16) * 64 + qx;

    // ================= phase 0: A(mi0-3), B(ni0-1); stage A1(t+1) ========
#pragma unroll
    for (int mi = 0; mi < 4; ++mi) {
      a[mi][0] = ld_frag(pa + mi * 1024 + kof0);
      a[mi][1] = ld_frag(pa + mi * 1024 + kof1);
    }
#pragma unroll
    for (int ni = 0; ni < 2; ++ni) {
      b01[ni][0] = ld_frag(pb + ni * 1024 + kof0);
      b01[ni][1] = ld_frag(pb + ni * 1024 + kof1);
    }
    if (tt < 15) stage_a(tt + 1, 1);
    __builtin_amdgcn_s_barrier();
    asm volatile("s_waitcnt lgkmcnt(0)" ::: "memory");
    __builtin_amdgcn_sched_barrier(0);
    __builtin_amdgcn_s_setprio(1);
#pragma unroll
    for (int mi = 0; mi < 4; ++mi)
#pragma unroll
      for (int ni = 0; ni < 2; ++ni) {
        acc[mi][ni] = __builtin_amdgcn_mfma_f32_16x16x32_bf16(a[mi][0], b01[ni][0], acc[mi][ni], 0, 0, 0);
        acc[mi][ni] = __builtin_amdgcn_mfma_f32_16x16x32_bf16(a[mi][1], b01[ni][1], acc[mi][ni], 0, 0, 0);
      }
    __builtin_amdgcn_s_setprio(0);
    __builtin_amdgcn_s_barrier();

    // ================= phase 1: B(ni2-3); no stage =======================
#pragma unroll
    for (int ni = 0; ni < 2; ++ni) {
      b23[ni][0] = ld_frag(pb + (ni + 2) * 1024 + kof0);
      b23[ni][1] = ld_frag(pb + (ni + 2) * 1024 + kof1);
    }
    __builtin_amdgcn_s_barrier();
    asm volatile("s_waitcnt lgkmcnt(0)" ::: "memory");
    __builtin_amdgcn_sched_barrier(0);
    __builtin_amdgcn_s_setprio(1);
#pragma unroll
    for (int mi = 0; mi < 4; ++mi)
#pragma unroll
      for (int ni = 0; ni < 2; ++ni) {
        acc[mi][ni + 2] = __builtin_amdgcn_mfma_f32_16x16x32_bf16(a[mi][0], b23[ni][0], acc[mi][ni + 2], 0, 0, 0);
        acc[mi][ni + 2] = __builtin_amdgcn_mfma_f32_16x16x32_bf16(a[mi][1], b23[ni][1], acc[mi][ni + 2], 0, 0, 0);
      }
    __builtin_amdgcn_s_setprio(0);
    __builtin_amdgcn_s_barrier();

    // ================= phase 2: A(mi4-7); stage B0(t+2) ==================
    // (B-half0 of current buf fully read as of P1's lgkmcnt+barrier.)
#pragma unroll
    for (int mi = 0; mi < 4; ++mi) {
      a[mi][0] = ld_frag(pa + (mi + 4) * 1024 + kof0);
      a[mi][1] = ld_frag(pa + (mi + 4) * 1024 + kof1);
    }
    if (tt < 14) stage_b(tt + 2, 0);
    __builtin_amdgcn_s_barrier();
    asm volatile("s_waitcnt lgkmcnt(0)" ::: "memory");
    __builtin_amdgcn_sched_barrier(0);
    __builtin_amdgcn_s_setprio(1);
#pragma unroll
    for (int mi = 0; mi < 4; ++mi)
#pragma unroll
      for (int ni = 0; ni < 2; ++ni) {
        acc[mi + 4][ni + 2] = __builtin_amdgcn_mfma_f32_16x16x32_bf16(a[mi][0], b23[ni][0], acc[mi + 4][ni + 2], 0, 0, 0);
        acc[mi + 4][ni + 2] = __builtin_amdgcn_mfma_f32_16x16x32_bf16(a[mi][1], b23[ni][1], acc[mi + 4][ni + 2], 0, 0, 0);
      }
    __builtin_amdgcn_s_setprio(0);
    __builtin_amdgcn_s_barrier();

    // ================= phase 3: no reads; stage A0(t+2), B1(t+2) =========
    // (A-halves of current buf fully read as of P2's lgkmcnt+barrier.)
    if (tt < 14) { stage_a(tt + 2, 0); stage_b(tt + 2, 1); }
    __builtin_amdgcn_s_barrier();
    __builtin_amdgcn_s_setprio(1);
#pragma unroll
    for (int mi = 0; mi < 4; ++mi)
#pragma unroll
      for (int ni = 0; ni < 2; ++ni) {
        acc[mi + 4][ni] = __builtin_amdgcn_mfma_f32_16x16x32_bf16(a[mi][0], b01[ni][0], acc[mi + 4][ni], 0, 0, 0);
        acc[mi + 4][ni] = __builtin_amdgcn_mfma_f32_16x16x32_bf16(a[mi][1], b01[ni][1], acc[mi + 4][ni], 0, 0, 0);
      }
    __builtin_amdgcn_s_setprio(0);
    // ---- K-tile boundary: counted vmcnt, never 0 in steady state ----
    if (tt < 15) {
      if (tt == 14) asm volatile("s_waitcnt vmcnt(0)" ::: "memory");
      else          asm volatile("s_waitcnt vmcnt(6)" ::: "memory");
      __builtin_amdgcn_s_barrier();
    }
  }

  // ---- epilogue ----
  const int rbase = m0 + wm * 128 + quad * 4;
  const int cbase = n0 + wn * 64 + l16;
  if (n0 < 1024) {   // K half: row-major bf16 + bk
#pragma unroll
    for (int mi = 0; mi < 8; ++mi)
#pragma unroll
      for (int ni = 0; ni < 4; ++ni) {
        const int cc = cbase + ni * 16;
        const float bb = bk_[cc];
        const int r0 = rbase + mi * 16;
#pragma unroll
        for (int rr = 0; rr < 4; ++rr)
          Kout[(size_t)(r0 + rr) * 1024 + cc] = f2bf(acc[mi][ni][rr] + bb);
      }
  } else {           // V half: transposed per head + bv
#pragma unroll
    for (int mi = 0; mi < 8; ++mi)
#pragma unroll
      for (int ni = 0; ni < 4; ++ni) {
        const int cv = cbase - 1024 + ni * 16;
        const int hh_ = cv >> 6, dd = cv & 63;
        const float bb = bv_[cv];
        const int gr0 = rbase + mi * 16 + mrow_off;
        const int bcl = gr0 >> 8, j0 = gr0 & 255;
        ushort4 o;
        o.x = f2bf(acc[mi][ni][0] + bb);
        o.y = f2bf(acc[mi][ni][1] + bb);
        o.z = f2bf(acc[mi][ni][2] + bb);
        o.w = f2bf(acc[mi][ni][3] + bb);
        *(ushort4*)&Vtg[(size_t)(bcl * 16 + hh_) * 16384 + dd * 256 + j0] = o;
      }
  }
}

// ---------------------------------------------------------------------------
// Attention: one block per (b, chunk, head). 256 threads (4 waves).
// ---------------------------------------------------------------------------
__global__ __launch_bounds__(256) void attn_kernel(const ushort* __restrict__ Qb,
                                                   const ushort* __restrict__ Kb,
                                                   const ushort* __restrict__ Vtg,
                                                   ushort* __restrict__ Ob) {
  __shared__ __align__(16) ushort smem[4608 + 18432 + 16896];   // 79872 B
  __shared__ float redm[4][64];
  __shared__ float reds[4][64];
  ushort* Qs = smem;
  ushort* Ks = smem + 4608;
  ushort* Vt = smem + 23040;
  ushort* Ps = smem;

  const int t = threadIdx.x;
  const int bx = blockIdx.x;
  const int hd = bx & 15, c = (bx >> 4) & 31, b = bx >> 9;
  const int lane = t & 63, wave = t >> 6;
  const int quad = lane >> 4, l16 = lane & 15;

  const int qrow0 = b * 2048 + c * 64;
  const int kvrow0 = (b * 32 + c) * 256;
  const int colh = hd * 64;
  const ushort* vsrc = Vtg + ((size_t)((b * 32 + c) * 16 + hd)) * 16384;

#pragma unroll
  for (int it = 0; it < 2; ++it) {
    int lid = it * 256 + t;
    int r = lid >> 3, ch = (lid & 7) * 8;
    uint4 v = *(const uint4*)&Qb[(size_t)(qrow0 + r) * 1024 + colh + ch];
    *(uint4*)&Qs[r * 72 + ch] = v;
  }
#pragma unroll
  for (int it = 0; it < 8; ++it) {
    int lid = it * 256 + t;
    int r = lid >> 3, ch = (lid & 7) * 8;
    uint4 v = *(const uint4*)&Kb[(size_t)(kvrow0 + r) * 1024 + colh + ch];
    *(uint4*)&Ks[r * 72 + ch] = v;
  }
#pragma unroll
  for (int it = 0; it < 8; ++it) {
    int lid = it * 256 + t;
    int row = lid >> 5, c8 = (lid & 31) * 8;
    uint4 v = *(const uint4*)&vsrc[row * 256 + c8];
    *(uint4*)&Vt[row * 264 + c8] = v;
  }
  __syncthreads();

  const int jw = wave * 64;
  f32x4 zero = {0.f, 0.f, 0.f, 0.f};
  f32x4 acc[4][4];
#pragma unroll
  for (int i = 0; i < 4; ++i)
#pragma unroll
    for (int j = 0; j < 4; ++j) acc[i][j] = zero;

#pragma unroll
  for (int kb = 0; kb < 2; ++kb) {
    bf16x8 af[4], bfv[4];
#pragma unroll
    for (int mi = 0; mi < 4; ++mi)
      af[mi] = ld_frag(&Qs[(mi * 16 + l16) * 72 + kb * 32 + quad * 8]);
#pragma unroll
    for (int mj = 0; mj < 4; ++mj)
      bfv[mj] = ld_frag(&Ks[(jw + mj * 16 + l16) * 72 + kb * 32 + quad * 8]);
#pragma unroll
    for (int mi = 0; mi < 4; ++mi)
#pragma unroll
      for (int mj = 0; mj < 4; ++mj)
        acc[mi][mj] = __builtin_amdgcn_mfma_f32_16x16x32_bf16(af[mi], bfv[mj], acc[mi][mj], 0, 0, 0);
  }

  float rmax[4][4];
#pragma unroll
  for (int mi = 0; mi < 4; ++mi)
#pragma unroll
    for (int rr = 0; rr < 4; ++rr) {
      float m = fmaxf(fmaxf(acc[mi][0][rr], acc[mi][1][rr]),
                      fmaxf(acc[mi][2][rr], acc[mi][3][rr]));
      m = fmaxf(m, __shfl_xor(m, 1));
      m = fmaxf(m, __shfl_xor(m, 2));
      m = fmaxf(m, __shfl_xor(m, 4));
      m = fmaxf(m, __shfl_xor(m, 8));
      rmax[mi][rr] = m;
    }
  if (l16 == 0) {
#pragma unroll
    for (int mi = 0; mi < 4; ++mi)
#pragma unroll
      for (int rr = 0; rr < 4; ++rr)
        redm[wave][mi * 16 + quad * 4 + rr] = rmax[mi][rr];
  }
  __syncthreads();
  float gmax[4][4];
#pragma unroll
  for (int mi = 0; mi < 4; ++mi)
#pragma unroll
    for (int rr = 0; rr < 4; ++rr) {
      const int row = mi * 16 + quad * 4 + rr;
      gmax[mi][rr] = fmaxf(fmaxf(redm[0][row], redm[1][row]),
                           fmaxf(redm[2][row], redm[3][row]));
    }
  float rsum[4][4];
#pragma unroll
  for (int mi = 0; mi < 4; ++mi)
#pragma unroll
    for (int rr = 0; rr < 4; ++rr) {
      float s = 0.f;
#pragma unroll
      for (int mj = 0; mj < 4; ++mj) {
        float p = exp2f((acc[mi][mj][rr] - gmax[mi][rr]) * 1.4426950408889634f);
        acc[mi][mj][rr] = p;
        s += p;
      }
      s += __shfl_xor(s, 1);
      s += __shfl_xor(s, 2);
      s += __shfl_xor(s, 4);
      s += __shfl_xor(s, 8);
      rsum[mi][rr] = s;
    }
  if (l16 == 0) {
#pragma unroll
    for (int mi = 0; mi < 4; ++mi)
#pragma unroll
      for (int rr = 0; rr < 4; ++rr)
        reds[wave][mi * 16 + quad * 4 + rr] = rsum[mi][rr];
  }
  __syncthreads();
#pragma unroll
  for (int mi = 0; mi < 4; ++mi)
#pragma unroll
    for (int rr = 0; rr < 4; ++rr) {
      const int row = mi * 16 + quad * 4 + rr;
      const float inv = 1.0f / (reds[0][row] + reds[1][row] + reds[2][row] + reds[3][row]);
#pragma unroll
      for (int mj = 0; mj < 4; ++mj)
        Ps[row * 264 + jw + mj * 16 + l16] = f2bf(acc[mi][mj][rr] * inv);
    }
  __syncthreads();

  const int d0 = wave * 16;
  f32x4 acc2[4];
#pragma unroll
  for (int mi = 0; mi < 4; ++mi) acc2[mi] = zero;
#pragma unroll
  for (int kb = 0; kb < 8; ++kb) {
    bf16x8 bfv = ld_frag(&Vt[(d0 + l16) * 264 + kb * 32 + quad * 8]);
#pragma unroll
    for (int mi = 0; mi < 4; ++mi) {
      bf16x8 af = ld_frag(&Ps[(mi * 16 + l16) * 264 + kb * 32 + quad * 8]);
      acc2[mi] = __builtin_amdgcn_mfma_f32_16x16x32_bf16(af, bfv, acc2[mi], 0, 0, 0);
    }
  }
#pragma unroll
  for (int mi = 0; mi < 4; ++mi)
#pragma unroll
    for (int rr = 0; rr < 4; ++rr) {
      const int i = mi * 16 + quad * 4 + rr;
      Ob[(size_t)(qrow0 + i) * 1024 + colh + d0 + l16] = f2bf(acc2[mi][rr]);
    }
}

// ---------------------------------------------------------------------------
// head rows 0..62 of each batch: pure residual copy
// ---------------------------------------------------------------------------
__global__ __launch_bounds__(256) void head_copy(const float* __restrict__ h,
                                                 float* __restrict__ out) {
  const int idx4 = blockIdx.x * 256 + threadIdx.x;   // 0 .. 64511
  const int b = idx4 / 16128;
  const int rem = idx4 - b * 16128;
  const size_t o = (size_t)b * 2048 * 1024 + (size_t)rem * 4;
  *(float4*)&out[o] = *(const float4*)&h[o];
}

// ---------------------------------------------------------------------------
extern "C" void kernel_launch(void* const* d_in, const int* in_sizes, int n_in,
                              void* d_out, int out_size, void* d_ws, size_t ws_size,
                              hipStream_t stream) {
  const float* h     = (const float*)d_in[0];
  const float* e     = (const float*)d_in[1];
  const float* Wq    = (const float*)d_in[2];
  const float* bq    = (const float*)d_in[3];
  const float* Wk    = (const float*)d_in[4];
  const float* bk    = (const float*)d_in[5];
  const float* Wv    = (const float*)d_in[6];
  const float* bv    = (const float*)d_in[7];
  const float* Wo    = (const float*)d_in[8];
  const float* bo    = (const float*)d_in[9];
  const float* gamma = (const float*)d_in[10];
  const float* beta  = (const float*)d_in[11];
  float* out = (float*)d_out;

  // Workspace layout (exactly 184 MiB, proven safe):
  char* ws = (char*)d_ws;
  ushort* stg  = (ushort*)(ws + ((size_t)0 << 20));    // 32 MiB
  ushort* WqT  = (ushort*)(ws + ((size_t)32 << 20));   // 2 MiB
  ushort* WkvT = (ushort*)(ws + ((size_t)34 << 20));   // 4 MiB (Wk | Wv)
  ushort* WoT  = (ushort*)(ws + ((size_t)38 << 20));   // 2 MiB
  ushort* Qb   = (ushort*)(ws + ((size_t)40 << 20));   // 16 MiB
  ushort* Kb   = (ushort*)(ws + ((size_t)56 << 20));   // 64 MiB
  ushort* VtG  = (ushort*)(ws + ((size_t)120 << 20));  // 64 MiB ([bch][64][256])

  // 1. weights -> bf16 transposed (one dispatch)
  transpose_cast4<<<dim3(16, 16, 4), 256, 0, stream>>>(Wq, Wk, Wv, Wo, WqT, WkvT, WoT);

  // 2. LayerNorm -> stg[0:16M] (bf16, padded)
  ln_kernel<<<8192, 256, 0, stream>>>(h, gamma, beta, stg);

  // 3. Q projection (scale 1/8 folded in; consumes LN output)
  gemm_bf16<0, 8><<<512, 256, 0, stream>>>(stg, WqT, bq, nullptr, Qb, nullptr,
                                           nullptr, nullptr, 64, 0.125f, 0);

  // 4. fused K|V projection in 2 halves of 16384 rows (e cast through stg),
  //    256x256 8-phase kernel: 64 mtiles x 8 ntiles = 512 blocks x 512 thr.
  for (int half = 0; half < 2; ++half) {
    const size_t roff = (size_t)half * 16384 * 1024;
    cast_bf16<<<8192, 256, 0, stream>>>(e + roff, stg);
    gemm_kv256<<<512, 512, 0, stream>>>(stg, WkvT, bk, bv, Kb + roff,
                                        VtG, half * 16384);
  }

  // 5. attention per (b, chunk, head) -> Ob (= stg, dead region)
  attn_kernel<<<2048, 256, 0, stream>>>(Qb, Kb, VtG, stg);

  // 6. output projection + shifted residual (f32 out), plus first-63-row copy
  gemm_bf16<1, 8><<<512, 256, 0, stream>>>(stg, WoT, bo, nullptr, nullptr, nullptr,
                                           out, h, 64, 1.0f, 0);
  head_copy<<<252, 256, 0, stream>>>(h, out);
}